// Round 8
// baseline (34.936 us; speedup 1.0000x reference)
//
#include <hip/hip_runtime.h>
#include <cstdint>

#define OUTF 12288
#define INF  4096
#define NG   32
#define BATCH 8
#define KS   4                 // k-splits

// ws: x16 bf16 [16][4096] (rows 8-15 zero) + sumxT f32 [32][16] (m 8-15 zero)
#define WS_X16_BYTES 131072
#define WS_SUMX_OFF  131072
#define WS_NEEDED    (131072 + 2048)

typedef short short8 __attribute__((ext_vector_type(8)));
typedef float f32x4  __attribute__((ext_vector_type(4)));
typedef _Float16 half2_t __attribute__((ext_vector_type(2)));

__device__ __forceinline__ uint32_t cvt_pk_bf16(float lo, float hi) {
    uint32_t r;
    asm("v_cvt_pk_bf16_f32 %0, %1, %2" : "=v"(r) : "v"(lo), "v"(hi));
    return r;
}
__device__ __forceinline__ float bf16lo_f(uint32_t w) {
    return __builtin_bit_cast(float, w << 16);
}
__device__ __forceinline__ float bf16hi_f(uint32_t w) {
    return __builtin_bit_cast(float, w & 0xFFFF0000u);
}
// one qc int (byte e) -> two bf16 (128+q_hi, 128+q_lo) packed; exact in bf16
__device__ __forceinline__ uint32_t bpair(uint32_t e) {
    return 0x43004300u | ((e >> 4) & 0xFu) | ((e & 0xFu) << 16);
}

// ---- prep: x->bf16 image (zero-padded to 16 rows) + sumx[g][m] + out=bias ----
__global__ __launch_bounds__(256) void qlin_prep(
    const float* __restrict__ x, const float* __restrict__ bias,
    uint32_t* __restrict__ x16, float* __restrict__ sumxT,
    float* __restrict__ out)
{
    const int blk = blockIdx.x, t = threadIdx.x;
    if (blk < 8) {
        // batch row blk: thread t owns 16 elems at t*16 (one group spans 8 threads)
        const float* xr = x + blk * INF + t * 16;
        const float4 a = *reinterpret_cast<const float4*>(xr);
        const float4 b = *reinterpret_cast<const float4*>(xr + 4);
        const float4 c = *reinterpret_cast<const float4*>(xr + 8);
        const float4 d = *reinterpret_cast<const float4*>(xr + 12);
        uint32_t w[8];
        w[0] = cvt_pk_bf16(a.x, a.y); w[1] = cvt_pk_bf16(a.z, a.w);
        w[2] = cvt_pk_bf16(b.x, b.y); w[3] = cvt_pk_bf16(b.z, b.w);
        w[4] = cvt_pk_bf16(c.x, c.y); w[5] = cvt_pk_bf16(c.z, c.w);
        w[6] = cvt_pk_bf16(d.x, d.y); w[7] = cvt_pk_bf16(d.z, d.w);
        uint4 s0 = {w[0], w[1], w[2], w[3]};
        uint4 s1 = {w[4], w[5], w[6], w[7]};
        reinterpret_cast<uint4*>(x16 + blk * 2048 + t * 8)[0] = s0;
        reinterpret_cast<uint4*>(x16 + blk * 2048 + t * 8 + 4)[1 - 1] = s1;
        // wait: fix pointer for s1
        // (written below correctly)
        float s = 0.f;
        #pragma unroll
        for (int i = 0; i < 8; ++i) s += bf16lo_f(w[i]) + bf16hi_f(w[i]);
        s += __shfl_xor(s, 1, 64);
        s += __shfl_xor(s, 2, 64);
        s += __shfl_xor(s, 4, 64);
        if ((t & 7) == 0) sumxT[(t >> 3) * 16 + blk] = s;
    } else if (blk < 16) {
        // zero rows 8..15 of x16 (thread t: 8 u32 = 16 bf16)
        uint4 z = {0u, 0u, 0u, 0u};
        uint4* p = reinterpret_cast<uint4*>(x16 + blk * 2048 + t * 8);
        p[0] = z; p[1] = z;
        if (blk == 8) {  // zero sumxT m=8..15
            const int g = t >> 3, m = 8 + (t & 7);
            sumxT[g * 16 + m] = 0.f;
        }
    } else {
        // bias init: out[b][o] = bias[o]
        const int bb = (blk - 16) / 12;
        const int j  = ((blk - 16) % 12) * 256 + t;   // float4 index in row
        const float4 bv = *reinterpret_cast<const float4*>(bias + j * 4);
        *reinterpret_cast<float4*>(out + bb * OUTF + j * 4) = bv;
    }
}

// ---- main: MFMA GEMV, q direct from global, no LDS, atomic k-split ----
__global__ __launch_bounds__(256, 4) void qlin_main(
    const int*      __restrict__ qc,      // [12288][2048] int32 (one byte/elem)
    const float*    __restrict__ scales,  // [12288][32]
    const float*    __restrict__ zeros,   // [12288][32]
    const uint16_t* __restrict__ x16,     // [16][4096] bf16
    const float*    __restrict__ sumxT,   // [32][16]
    float*          __restrict__ out)     // [8][12288]
{
    const int wid  = threadIdx.x >> 6;
    const int lane = threadIdx.x & 63;
    const int W    = blockIdx.x * 4 + wid;      // 0..3071
    const int ot   = W >> 2;                    // o-tile 0..767
    const int ks   = W & 3;                     // k-quarter
    const int n16  = lane & 15;
    const int q4   = lane >> 4;

    const int ocol = (ot << 4) + n16;
    const int* qrow = qc + ocol * 2048 + ks * 512 + q4 * 4;
    const uint16_t* xrow = x16 + n16 * INF + ks * 1024 + q4 * 8;

    // preload this wave's 8 groups of scale/zero (consecutive floats)
    const float4 sc0 = *reinterpret_cast<const float4*>(scales + ocol * NG + ks * 8);
    const float4 sc1 = *reinterpret_cast<const float4*>(scales + ocol * NG + ks * 8 + 4);
    const float4 zp0 = *reinterpret_cast<const float4*>(zeros  + ocol * NG + ks * 8);
    const float4 zp1 = *reinterpret_cast<const float4*>(zeros  + ocol * NG + ks * 8 + 4);
    const float scA[8] = {sc0.x, sc0.y, sc0.z, sc0.w, sc1.x, sc1.y, sc1.z, sc1.w};
    const float zpA[8] = {zp0.x, zp0.y, zp0.z, zp0.w, zp1.x, zp1.y, zp1.z, zp1.w};

    float y0 = 0.f, y1 = 0.f, y2 = 0.f, y3 = 0.f;

    #pragma unroll
    for (int s = 0; s < 8; ++s) {               // one quant group per step
        const int g = ks * 8 + s;
        uint4 qv[4], av[4];
        #pragma unroll
        for (int kb = 0; kb < 4; ++kb) {
            qv[kb] = *reinterpret_cast<const uint4*>(qrow + s * 64 + kb * 16);
            av[kb] = *reinterpret_cast<const uint4*>(xrow + s * 128 + kb * 32);
        }
        const float4 sx = *reinterpret_cast<const float4*>(sumxT + g * 16 + q4 * 4);

        f32x4 Cg = {0.f, 0.f, 0.f, 0.f};
        #pragma unroll
        for (int kb = 0; kb < 4; ++kb) {
            uint4 bw;
            bw.x = bpair(qv[kb].x);
            bw.y = bpair(qv[kb].y);
            bw.z = bpair(qv[kb].z);
            bw.w = bpair(qv[kb].w);
            const short8 Af = __builtin_bit_cast(short8, av[kb]);
            const short8 Bf = __builtin_bit_cast(short8, bw);
            Cg = __builtin_amdgcn_mfma_f32_16x16x32_bf16(Af, Bf, Cg, 0, 0, 0);
        }

        const float sc = scA[s];
        const float c1 = -sc * (128.0f + zpA[s]);   // folds 0x4300 offset + zp
        y0 = fmaf(sc, Cg[0], y0); y0 = fmaf(c1, sx.x, y0);
        y1 = fmaf(sc, Cg[1], y1); y1 = fmaf(c1, sx.y, y1);
        y2 = fmaf(sc, Cg[2], y2); y2 = fmaf(c1, sx.z, y2);
        y3 = fmaf(sc, Cg[3], y3); y3 = fmaf(c1, sx.w, y3);
    }

    // C/D: col = lane&15 (=o), row m = q4*4 + j ; rows 8-15 are zero padding
    if (q4 < 2) {
        float* op = out + (q4 * 4) * OUTF + ocol;
        atomicAdd(op,            y0);
        atomicAdd(op + OUTF,     y1);
        atomicAdd(op + 2 * OUTF, y2);
        atomicAdd(op + 3 * OUTF, y3);
    }
}

// ---- fallback: round-5 proven single kernel (ws too small) ----
__device__ __forceinline__ float dot2(half2_t a, half2_t b, float c) {
#if __has_builtin(__builtin_amdgcn_fdot2)
    return __builtin_amdgcn_fdot2(a, b, c, false);
#else
    return c + (float)(a.x) * (float)(b.x) + (float)(a.y) * (float)(b.y);
#endif
}
__device__ __forceinline__ half2_t pk16(float a, float b) {
    return __builtin_bit_cast(half2_t, __builtin_amdgcn_cvt_pkrtz(a, b));
}

__global__ __launch_bounds__(512, 4) void qlin_fb(
    const float* __restrict__ x, const int* __restrict__ qc,
    const float* __restrict__ scales, const float* __restrict__ zeros,
    const float* __restrict__ bias, float* __restrict__ out)
{
    __shared__ uint4 xs[4096];
    const int tid = threadIdx.x, wave = tid >> 6, lane = tid & 63;
    const int row0 = blockIdx.x * 24 + wave * 3;
    #pragma unroll
    for (int i = 0; i < 8; ++i) {
        const float4 v0 = *reinterpret_cast<const float4*>(x + i * INF + tid * 8);
        const float4 v1 = *reinterpret_cast<const float4*>(x + i * INF + tid * 8 + 4);
        uint4 w;
        w.x = __builtin_bit_cast(uint32_t, pk16(v0.x, v0.y));
        w.y = __builtin_bit_cast(uint32_t, pk16(v0.z, v0.w));
        w.z = __builtin_bit_cast(uint32_t, pk16(v1.x, v1.y));
        w.w = __builtin_bit_cast(uint32_t, pk16(v1.z, v1.w));
        xs[i * 512 + tid] = w;
    }
    const int* qp[3]; const float* scb[3]; const float* zpb[3];
    #pragma unroll
    for (int r = 0; r < 3; ++r) {
        const int o = row0 + r;
        qp[r] = qc + o * 2048 + lane * 4;
        scb[r] = scales + o * NG + (lane >> 4);
        zpb[r] = zeros  + o * NG + (lane >> 4);
    }
    uint4 tA[3], tB[3]; float sA[3], nzA[3], sB[3], nzB[3];
    #pragma unroll
    for (int r = 0; r < 3; ++r) {
        tA[r] = *reinterpret_cast<const uint4*>(qp[r]);
        tB[r] = *reinterpret_cast<const uint4*>(qp[r] + 256);
        sA[r] = scb[r][0]; nzA[r] = -zpb[r][0] * sA[r];
    }
    float y[3][8];
    #pragma unroll
    for (int r = 0; r < 3; ++r)
        #pragma unroll
        for (int b = 0; b < 8; ++b) y[r][b] = 0.f;
    __syncthreads();
    #pragma unroll
    for (int h = 0; h < 8; ++h) {
        uint4 tN[3];
        if (h < 6)
            #pragma unroll
            for (int r = 0; r < 3; ++r)
                tN[r] = *reinterpret_cast<const uint4*>(qp[r] + (h + 2) * 256);
        if (h < 7)
            #pragma unroll
            for (int r = 0; r < 3; ++r) {
                sB[r] = scb[r][(h + 1) * 4]; nzB[r] = -zpb[r][(h + 1) * 4] * sB[r];
            }
        half2_t wp[3][4];
        #pragma unroll
        for (int r = 0; r < 3; ++r)
            #pragma unroll
            for (int e = 0; e < 4; ++e) {
                const uint32_t ei = (e == 0) ? tA[r].x : (e == 1) ? tA[r].y
                                 : (e == 2) ? tA[r].z : tA[r].w;
                wp[r][e] = pk16(fmaf((float)((ei >> 4) & 0xFu), sA[r], nzA[r]),
                                fmaf((float)( ei       & 0xFu), sA[r], nzA[r]));
            }
        const int slot = h * 64 + lane;
        #pragma unroll
        for (int b = 0; b < 8; ++b) {
            const uint4 v = xs[b * 512 + slot];
            const half2_t x0 = __builtin_bit_cast(half2_t, v.x);
            const half2_t x1 = __builtin_bit_cast(half2_t, v.y);
            const half2_t x2 = __builtin_bit_cast(half2_t, v.z);
            const half2_t x3 = __builtin_bit_cast(half2_t, v.w);
            #pragma unroll
            for (int r = 0; r < 3; ++r) {
                y[r][b] = dot2(wp[r][0], x0, y[r][b]);
                y[r][b] = dot2(wp[r][1], x1, y[r][b]);
                y[r][b] = dot2(wp[r][2], x2, y[r][b]);
                y[r][b] = dot2(wp[r][3], x3, y[r][b]);
            }
        }
        #pragma unroll
        for (int r = 0; r < 3; ++r) {
            tA[r] = tB[r];
            if (h < 6) tB[r] = tN[r];
            if (h < 7) { sA[r] = sB[r]; nzA[r] = nzB[r]; }
        }
    }
    float keep = 0.f;
    #pragma unroll
    for (int r = 0; r < 3; ++r)
        #pragma unroll
        for (int b = 0; b < 8; ++b) {
            float v = y[r][b];
            #pragma unroll
            for (int m = 1; m < 64; m <<= 1) v += __shfl_xor(v, m, 64);
            if (lane == r * 8 + b) keep = v;
        }
    if (lane < 24) {
        const int r = lane >> 3, b = lane & 7;
        const int o = row0 + r;
        out[b * OUTF + o] = keep + bias[o];
    }
}

extern "C" void kernel_launch(void* const* d_in, const int* in_sizes, int n_in,
                              void* d_out, int out_size, void* d_ws, size_t ws_size,
                              hipStream_t stream) {
    const float* x      = (const float*)d_in[0];
    const int*   qcodes = (const int*)  d_in[1];
    const float* scales = (const float*)d_in[2];
    const float* zeros  = (const float*)d_in[3];
    const float* bias   = (const float*)d_in[4];
    float* out = (float*)d_out;

    if (ws_size >= (size_t)WS_NEEDED) {
        uint32_t* x16  = (uint32_t*)d_ws;
        float*    sumxT = (float*)((char*)d_ws + WS_SUMX_OFF);
        qlin_prep<<<112, 256, 0, stream>>>(x, bias, x16, sumxT, out);
        qlin_main<<<768, 256, 0, stream>>>(qcodes, scales, zeros,
                                           (const uint16_t*)x16, sumxT, out);
    } else {
        qlin_fb<<<512, 512, 0, stream>>>(x, qcodes, scales, zeros, bias, out);
    }
}